// Round 4
// baseline (494.661 us; speedup 1.0000x reference)
//
#include <hip/hip_runtime.h>

#define DIM 512
#define HIDDEN 1024
#define H2 2048        // 2*HIDDEN
#define NEXP 32
#define TOPK 4
#define TOKENS 64
#define NPAIR (TOKENS*TOPK)   // 256

// ---------------- router: logits + top4 + softmax ----------------
__global__ void router_kernel(const float* __restrict__ x, const float* __restrict__ Wg,
                              const float* __restrict__ bg, int* __restrict__ idxw,
                              float* __restrict__ eww) {
    int b = blockIdx.x;
    int e = threadIdx.x;          // 64 threads, first 32 compute logits
    __shared__ float g[NEXP];
    if (e < NEXP) {
        const float* xr = x + b * DIM;
        const float* wr = Wg + e * DIM;
        float acc = 0.f;
        for (int d = 0; d < DIM; d += 4) {
            float4 xv = *(const float4*)(xr + d);
            float4 wv = *(const float4*)(wr + d);
            acc += xv.x*wv.x + xv.y*wv.y + xv.z*wv.z + xv.w*wv.w;
        }
        g[e] = acc + bg[e];
    }
    __syncthreads();
    if (threadIdx.x == 0) {
        int sel[TOPK]; float val[TOPK];
        bool used[NEXP];
        for (int i = 0; i < NEXP; ++i) used[i] = false;
        for (int k = 0; k < TOPK; ++k) {
            float best = -1e30f; int bi = 0;
            for (int ee = 0; ee < NEXP; ++ee) {
                if (!used[ee] && g[ee] > best) { best = g[ee]; bi = ee; }
            }
            used[bi] = true; sel[k] = bi; val[k] = best;
        }
        float m = val[0];        // val[0] is the max
        float p[TOPK]; float s = 0.f;
        for (int k = 0; k < TOPK; ++k) { p[k] = __expf(val[k] - m); s += p[k]; }
        float inv = 1.f / s;
        for (int k = 0; k < TOPK; ++k) {
            idxw[b*TOPK + k] = sel[k];
            eww[b*TOPK + k]  = p[k] * inv;
        }
    }
}

// ---------------- deterministic per-expert list build ----------------
__global__ void build_lists(const int* __restrict__ idxw, int* __restrict__ counts,
                            int* __restrict__ lists) {
    int e = threadIdx.x;
    if (e >= NEXP) return;
    int cnt = 0;
    for (int p = 0; p < NPAIR; ++p) {
        if (idxw[p] == e) lists[e*TOKENS + cnt++] = p;
    }
    counts[e] = cnt;
}

// ---------------- expert up-proj + swiglu (16-way split-K, batched loads) ----------------
// block: 256 thr = 16 channel-pairs x 16 splits. grid: (NEXP, HIDDEN/16 = 64)
#define TC 8
__global__ __launch_bounds__(256, 4) void expert_up(
        const float* __restrict__ x, const float* __restrict__ w1,
        const float* __restrict__ b1, const int* __restrict__ counts,
        const int* __restrict__ lists, float* __restrict__ act) {
    int e = blockIdx.x;
    int n = counts[e];
    if (n == 0) return;
    int tid = threadIdx.x;
    int cl = tid >> 4;                    // 0..15
    int s  = tid & 15;                    // 0..15
    int c = blockIdx.y * 16 + cl;         // activation channel 0..1023
    // rows 2c and 2c+1 are contiguous in w1
    const float4* w0p = (const float4*)(w1 + ((size_t)e*H2 + 2*c) * DIM) + s;
    const float4* w1p = w0p + DIM/4;
    __shared__ float xs[TC][DIM];         // 16 KB
    for (int t0 = 0; t0 < n; t0 += TC) {
        int tc = min(TC, n - t0);
        __syncthreads();   // protect xs from previous iteration's readers
        for (int i = tid; i < TC*(DIM/4); i += 256) {
            int j = i >> 7; int dd = i & 127;          // DIM/4 = 128
            float4 v = make_float4(0.f, 0.f, 0.f, 0.f);
            if (j < tc) {
                int p = lists[e*TOKENS + t0 + j];
                int tok = p >> 2;
                v = *(const float4*)(x + (size_t)tok*DIM + dd*4);
            }
            *(float4*)&xs[j][dd*4] = v;
        }
        // Issue ALL 16 weight loads before the barrier/compute: 64 VGPRs of
        // in-flight loads -> one latency exposure instead of eight.
        float4 wb0[8], wb1[8];
        #pragma unroll
        for (int i = 0; i < 8; ++i) wb0[i] = w0p[16*i];
        #pragma unroll
        for (int i = 0; i < 8; ++i) wb1[i] = w1p[16*i];
        __syncthreads();
        float a0[TC], a1[TC];
        #pragma unroll
        for (int j = 0; j < TC; ++j) { a0[j] = 0.f; a1[j] = 0.f; }
        #pragma unroll
        for (int i = 0; i < 8; ++i) {                  // 128 f4 / 16 splits
            int d4 = s + 16*i;
            #pragma unroll
            for (int j = 0; j < TC; ++j) {
                float4 xv = *(const float4*)&xs[j][d4*4];
                a0[j] += wb0[i].x*xv.x + wb0[i].y*xv.y + wb0[i].z*xv.z + wb0[i].w*xv.w;
                a1[j] += wb1[i].x*xv.x + wb1[i].y*xv.y + wb1[i].z*xv.z + wb1[i].w*xv.w;
            }
        }
        // reduce across the 16 aligned lanes of the split group
        #pragma unroll
        for (int j = 0; j < TC; ++j) {
            #pragma unroll
            for (int m = 1; m < 16; m <<= 1) {
                a0[j] += __shfl_xor(a0[j], m);
                a1[j] += __shfl_xor(a1[j], m);
            }
        }
        if (s == 0) {
            float be = b1[e*H2 + 2*c];
            float bo = b1[e*H2 + 2*c + 1];
            for (int j = 0; j < tc; ++j) {
                int p = lists[e*TOKENS + t0 + j];
                float h0 = a0[j] + be;
                float h1 = a1[j] + bo;
                float gv = fminf(h0, 7.f);
                float lv = fminf(fmaxf(h1, -7.f), 7.f);
                float sg = 1.f / (1.f + __expf(-1.702f * gv));
                act[(size_t)p*HIDDEN + c] = gv * sg * (lv + 1.f);
            }
        }
    }
}

// ---------------- expert down-proj (16-way split-K, batched loads) ----------------
// block: 256 thr = 16 channels x 16 splits. grid: (NEXP, DIM/16 = 32)
#define TCD 8
__global__ __launch_bounds__(256, 4) void expert_down(
        const float* __restrict__ act, const float* __restrict__ w2,
        const float* __restrict__ b2, const int* __restrict__ counts,
        const int* __restrict__ lists, float* __restrict__ h2) {
    int e = blockIdx.x;
    int n = counts[e];
    if (n == 0) return;
    int tid = threadIdx.x;
    int cl = tid >> 4;
    int s  = tid & 15;
    int c = blockIdx.y * 16 + cl;         // output dim 0..511
    const float4* wp = (const float4*)(w2 + ((size_t)e*DIM + c) * HIDDEN) + s;
    __shared__ float hs[TCD][HIDDEN];     // 32 KB
    for (int t0 = 0; t0 < n; t0 += TCD) {
        int tc = min(TCD, n - t0);
        __syncthreads();
        for (int i = tid; i < TCD*(HIDDEN/4); i += 256) {
            int j = i >> 8; int dd = i & 255;          // HIDDEN/4 = 256
            float4 v = make_float4(0.f, 0.f, 0.f, 0.f);
            if (j < tc) {
                int p = lists[e*TOKENS + t0 + j];
                v = *(const float4*)(act + (size_t)p*HIDDEN + dd*4);
            }
            *(float4*)&hs[j][dd*4] = v;
        }
        // all 16 weight loads in flight before compute
        float4 wb[16];
        #pragma unroll
        for (int i = 0; i < 16; ++i) wb[i] = wp[16*i];
        __syncthreads();
        float a[TCD];
        #pragma unroll
        for (int j = 0; j < TCD; ++j) a[j] = 0.f;
        #pragma unroll
        for (int i = 0; i < 16; ++i) {                 // 256 f4 / 16 splits
            int d4 = s + 16*i;
            #pragma unroll
            for (int j = 0; j < TCD; ++j) {
                float4 hv = *(const float4*)&hs[j][d4*4];
                a[j] += wb[i].x*hv.x + wb[i].y*hv.y + wb[i].z*hv.z + wb[i].w*hv.w;
            }
        }
        #pragma unroll
        for (int j = 0; j < TCD; ++j) {
            #pragma unroll
            for (int m = 1; m < 16; m <<= 1) {
                a[j] += __shfl_xor(a[j], m);
            }
        }
        if (s == 0) {
            float bb = b2[e*DIM + c];
            for (int j = 0; j < tc; ++j) {
                int p = lists[e*TOKENS + t0 + j];
                h2[(size_t)p*DIM + c] = a[j] + bb;
            }
        }
    }
}

// ---------------- weighted combine ----------------
__global__ void combine_kernel(const float* __restrict__ h2, const float* __restrict__ eww,
                               float* __restrict__ out) {
    int i = blockIdx.x * 256 + threadIdx.x;   // 0..32767
    int b = i / DIM;
    int c = i % DIM;
    float s = 0.f;
    #pragma unroll
    for (int k = 0; k < TOPK; ++k) {
        s += eww[b*TOPK + k] * h2[(size_t)(b*TOPK + k)*DIM + c];
    }
    out[i] = s;
}

extern "C" void kernel_launch(void* const* d_in, const int* in_sizes, int n_in,
                              void* d_out, int out_size, void* d_ws, size_t ws_size,
                              hipStream_t stream) {
    const float* x  = (const float*)d_in[0];
    const float* Wg = (const float*)d_in[1];
    const float* bg = (const float*)d_in[2];
    const float* w1 = (const float*)d_in[3];
    const float* b1 = (const float*)d_in[4];
    const float* w2 = (const float*)d_in[5];
    const float* b2 = (const float*)d_in[6];
    float* out = (float*)d_out;

    char* ws = (char*)d_ws;
    int*   idxw   = (int*)(ws);                 // 256 ints
    float* eww    = (float*)(ws + 1024);        // 256 floats
    int*   counts = (int*)(ws + 2048);          // 32 ints
    int*   lists  = (int*)(ws + 4096);          // 32*64 ints
    float* act    = (float*)(ws + 16384);                          // 256*1024 f32 = 1 MB
    float* h2     = (float*)(ws + 16384 + (size_t)NPAIR*HIDDEN*4); // 256*512 f32 = 512 KB

    router_kernel<<<TOKENS, 64, 0, stream>>>(x, Wg, bg, idxw, eww);
    build_lists<<<1, 32, 0, stream>>>(idxw, counts, lists);
    expert_up<<<dim3(NEXP, HIDDEN/16), 256, 0, stream>>>(x, w1, b1, counts, lists, act);
    expert_down<<<dim3(NEXP, DIM/16), 256, 0, stream>>>(act, w2, b2, counts, lists, h2);
    combine_kernel<<<TOKENS*DIM/256, 256, 0, stream>>>(h2, eww, out);
}

// Round 5
// 164.062 us; speedup vs baseline: 3.0151x; 3.0151x over previous
//
#include <hip/hip_runtime.h>

#define DIM 512
#define HIDDEN 1024
#define H2 2048        // 2*HIDDEN
#define NEXP 32
#define TOPK 4
#define TOKENS 64
#define NPAIR (TOKENS*TOPK)   // 256

__device__ __forceinline__ float dot4(float4 a, float4 b) {
    return a.x*b.x + a.y*b.y + a.z*b.z + a.w*b.w;
}

// ---------------- router: logits + top4 + softmax ----------------
__global__ void router_kernel(const float* __restrict__ x, const float* __restrict__ Wg,
                              const float* __restrict__ bg, int* __restrict__ idxw,
                              float* __restrict__ eww) {
    int b = blockIdx.x;
    int e = threadIdx.x;
    __shared__ float g[NEXP];
    if (e < NEXP) {
        const float* xr = x + b * DIM;
        const float* wr = Wg + e * DIM;
        float acc = 0.f;
        for (int d = 0; d < DIM; d += 4) {
            float4 xv = *(const float4*)(xr + d);
            float4 wv = *(const float4*)(wr + d);
            acc += xv.x*wv.x + xv.y*wv.y + xv.z*wv.z + xv.w*wv.w;
        }
        g[e] = acc + bg[e];
    }
    __syncthreads();
    if (threadIdx.x == 0) {
        int sel[TOPK]; float val[TOPK];
        bool used[NEXP];
        for (int i = 0; i < NEXP; ++i) used[i] = false;
        for (int k = 0; k < TOPK; ++k) {
            float best = -1e30f; int bi = 0;
            for (int ee = 0; ee < NEXP; ++ee) {
                if (!used[ee] && g[ee] > best) { best = g[ee]; bi = ee; }
            }
            used[bi] = true; sel[k] = bi; val[k] = best;
        }
        float m = val[0];
        float p[TOPK]; float s = 0.f;
        for (int k = 0; k < TOPK; ++k) { p[k] = __expf(val[k] - m); s += p[k]; }
        float inv = 1.f / s;
        for (int k = 0; k < TOPK; ++k) {
            idxw[b*TOPK + k] = sel[k];
            eww[b*TOPK + k]  = p[k] * inv;
        }
    }
}

// ---------------- deterministic per-expert list build ----------------
__global__ void build_lists(const int* __restrict__ idxw, int* __restrict__ counts,
                            int* __restrict__ lists) {
    int e = threadIdx.x;
    if (e >= NEXP) return;
    int cnt = 0;
    for (int p = 0; p < NPAIR; ++p) {
        if (idxw[p] == e) lists[e*TOKENS + cnt++] = p;
    }
    counts[e] = cnt;
}

// ---------------- expert up-proj + swiglu (wave-per-row-pair streaming) ----
// block = 256 thr = 4 waves; each wave streams 8 channel-pairs (4 KB each,
// 4 contiguous 1KB wave-loads, 2-deep prefetch). grid (NEXP, HIDDEN/32=32).
__global__ __launch_bounds__(256) void expert_up(
        const float* __restrict__ x, const float* __restrict__ w1,
        const float* __restrict__ b1, const int* __restrict__ counts,
        const int* __restrict__ lists, float* __restrict__ act) {
    int e = blockIdx.x;
    int n = counts[e];
    if (n == 0) return;
    int tid = threadIdx.x;
    int wv = tid >> 6, l = tid & 63;
    __shared__ float xs[16][DIM];          // 32 KB token tile
    for (int t0 = 0; t0 < n; t0 += 16) {
        int nn = min(16, n - t0);
        int no = (nn + 7) >> 3;            // octets in this tile (1 or 2)
        __syncthreads();
        for (int i = tid; i < 16*(DIM/4); i += 256) {
            int j = i >> 7, dd = i & 127;  // DIM/4 = 128
            float4 v = make_float4(0.f,0.f,0.f,0.f);
            if (j < nn) {
                int p = lists[e*TOKENS + t0 + j];
                v = *(const float4*)(x + (size_t)(p>>2)*DIM + 4*dd);
            }
            *(float4*)&xs[j][4*dd] = v;
        }
        __syncthreads();
        int c0 = blockIdx.y*32 + wv*8;     // first channel-pair of this wave
        const float* rbase = w1 + ((size_t)e*H2 + 2*c0)*DIM;
        // prefetch q=0: rows 2c (glu) then 2c+1 (lin), 4x contiguous 1KB
        float4 pa0 = *(const float4*)(rbase +       4*l);
        float4 pb0 = *(const float4*)(rbase + 256 + 4*l);
        float4 pa1 = *(const float4*)(rbase + 512 + 4*l);
        float4 pb1 = *(const float4*)(rbase + 768 + 4*l);
        for (int q = 0; q < 8; ++q) {
            float4 wa0 = pa0, wb0 = pb0, wa1 = pa1, wb1 = pb1;
            if (q < 7) {
                const float* rn = rbase + (size_t)(q+1)*2*DIM;
                pa0 = *(const float4*)(rn +       4*l);
                pb0 = *(const float4*)(rn + 256 + 4*l);
                pa1 = *(const float4*)(rn + 512 + 4*l);
                pb1 = *(const float4*)(rn + 768 + 4*l);
            }
            int c = c0 + q;
            for (int o = 0; o < no; ++o) {
                float a0[8], a1[8];
                #pragma unroll
                for (int j = 0; j < 8; ++j) { a0[j] = 0.f; a1[j] = 0.f; }
                #pragma unroll
                for (int j = 0; j < 8; ++j) {
                    float4 xa = *(const float4*)&xs[o*8+j][4*l];
                    float4 xb = *(const float4*)&xs[o*8+j][256+4*l];
                    a0[j] += dot4(wa0, xa) + dot4(wb0, xb);
                    a1[j] += dot4(wa1, xa) + dot4(wb1, xb);
                }
                #pragma unroll
                for (int m = 1; m < 64; m <<= 1) {
                    #pragma unroll
                    for (int j = 0; j < 8; ++j) {
                        a0[j] += __shfl_xor(a0[j], m);
                        a1[j] += __shfl_xor(a1[j], m);
                    }
                }
                // lane j takes token j's totals (cndmask chain, static idx)
                float s0 = a0[0], s1 = a1[0];
                #pragma unroll
                for (int j = 1; j < 8; ++j) {
                    if (l == j) { s0 = a0[j]; s1 = a1[j]; }
                }
                int tc8 = min(8, nn - 8*o);
                if (l < tc8) {
                    int p = lists[e*TOKENS + t0 + 8*o + l];
                    float h0 = s0 + b1[e*H2 + 2*c];
                    float h1 = s1 + b1[e*H2 + 2*c + 1];
                    float gv = fminf(h0, 7.f);
                    float lv = fminf(fmaxf(h1, -7.f), 7.f);
                    float sg = 1.f / (1.f + __expf(-1.702f * gv));
                    act[(size_t)p*HIDDEN + c] = gv * sg * (lv + 1.f);
                }
            }
        }
    }
}

// ---------------- expert down-proj (wave-per-row streaming) ---------------
// block = 256 thr = 4 waves; each wave streams 4 rows (4 KB each, 4x 1KB
// contiguous wave-loads, 2-deep prefetch). grid (NEXP, DIM/16=32).
__global__ __launch_bounds__(256) void expert_down(
        const float* __restrict__ act, const float* __restrict__ w2,
        const float* __restrict__ b2, const int* __restrict__ counts,
        const int* __restrict__ lists, float* __restrict__ h2) {
    int e = blockIdx.x;
    int n = counts[e];
    if (n == 0) return;
    int tid = threadIdx.x;
    int wv = tid >> 6, l = tid & 63;
    __shared__ float as[16][HIDDEN];       // 64 KB act tile
    for (int t0 = 0; t0 < n; t0 += 16) {
        int nn = min(16, n - t0);
        int no = (nn + 7) >> 3;
        __syncthreads();
        for (int i = tid; i < 16*(HIDDEN/4); i += 256) {
            int j = i >> 8, dd = i & 255;  // HIDDEN/4 = 256
            float4 v = make_float4(0.f,0.f,0.f,0.f);
            if (j < nn) {
                int p = lists[e*TOKENS + t0 + j];
                v = *(const float4*)(act + (size_t)p*HIDDEN + 4*dd);
            }
            *(float4*)&as[j][4*dd] = v;
        }
        __syncthreads();
        int r0 = blockIdx.y*16 + wv*4;     // first output row of this wave
        const float* rbase = w2 + ((size_t)e*DIM + r0)*HIDDEN;
        float4 p0 = *(const float4*)(rbase +       4*l);
        float4 p1 = *(const float4*)(rbase + 256 + 4*l);
        float4 p2 = *(const float4*)(rbase + 512 + 4*l);
        float4 p3 = *(const float4*)(rbase + 768 + 4*l);
        for (int q = 0; q < 4; ++q) {
            float4 w0 = p0, w1v = p1, w2v = p2, w3v = p3;
            if (q < 3) {
                const float* rn = rbase + (size_t)(q+1)*HIDDEN;
                p0 = *(const float4*)(rn +       4*l);
                p1 = *(const float4*)(rn + 256 + 4*l);
                p2 = *(const float4*)(rn + 512 + 4*l);
                p3 = *(const float4*)(rn + 768 + 4*l);
            }
            int r = r0 + q;
            for (int o = 0; o < no; ++o) {
                float a[8];
                #pragma unroll
                for (int j = 0; j < 8; ++j) a[j] = 0.f;
                #pragma unroll
                for (int j = 0; j < 8; ++j) {
                    float4 xa = *(const float4*)&as[o*8+j][      4*l];
                    float4 xb = *(const float4*)&as[o*8+j][256 + 4*l];
                    float4 xc = *(const float4*)&as[o*8+j][512 + 4*l];
                    float4 xd = *(const float4*)&as[o*8+j][768 + 4*l];
                    a[j] += dot4(w0, xa) + dot4(w1v, xb) + dot4(w2v, xc) + dot4(w3v, xd);
                }
                #pragma unroll
                for (int m = 1; m < 64; m <<= 1) {
                    #pragma unroll
                    for (int j = 0; j < 8; ++j) a[j] += __shfl_xor(a[j], m);
                }
                float s = a[0];
                #pragma unroll
                for (int j = 1; j < 8; ++j) {
                    if (l == j) s = a[j];
                }
                int tc8 = min(8, nn - 8*o);
                if (l < tc8) {
                    int p = lists[e*TOKENS + t0 + 8*o + l];
                    h2[(size_t)p*DIM + r] = s + b2[e*DIM + r];
                }
            }
        }
    }
}

// ---------------- weighted combine ----------------
__global__ void combine_kernel(const float* __restrict__ h2, const float* __restrict__ eww,
                               float* __restrict__ out) {
    int i = blockIdx.x * 256 + threadIdx.x;   // 0..32767
    int b = i / DIM;
    int c = i % DIM;
    float s = 0.f;
    #pragma unroll
    for (int k = 0; k < TOPK; ++k) {
        s += eww[b*TOPK + k] * h2[(size_t)(b*TOPK + k)*DIM + c];
    }
    out[i] = s;
}

extern "C" void kernel_launch(void* const* d_in, const int* in_sizes, int n_in,
                              void* d_out, int out_size, void* d_ws, size_t ws_size,
                              hipStream_t stream) {
    const float* x  = (const float*)d_in[0];
    const float* Wg = (const float*)d_in[1];
    const float* bg = (const float*)d_in[2];
    const float* w1 = (const float*)d_in[3];
    const float* b1 = (const float*)d_in[4];
    const float* w2 = (const float*)d_in[5];
    const float* b2 = (const float*)d_in[6];
    float* out = (float*)d_out;

    char* ws = (char*)d_ws;
    int*   idxw   = (int*)(ws);                 // 256 ints
    float* eww    = (float*)(ws + 1024);        // 256 floats
    int*   counts = (int*)(ws + 2048);          // 32 ints
    int*   lists  = (int*)(ws + 4096);          // 32*64 ints
    float* act    = (float*)(ws + 16384);                          // 256*1024 f32 = 1 MB
    float* h2     = (float*)(ws + 16384 + (size_t)NPAIR*HIDDEN*4); // 256*512 f32 = 512 KB

    router_kernel<<<TOKENS, 64, 0, stream>>>(x, Wg, bg, idxw, eww);
    build_lists<<<1, 32, 0, stream>>>(idxw, counts, lists);
    expert_up<<<dim3(NEXP, HIDDEN/32), 256, 0, stream>>>(x, w1, b1, counts, lists, act);
    expert_down<<<dim3(NEXP, DIM/16), 256, 0, stream>>>(act, w2, b2, counts, lists, h2);
    combine_kernel<<<TOKENS*DIM/256, 256, 0, stream>>>(h2, eww, out);
}

// Round 7
// 83.089 us; speedup vs baseline: 5.9534x; 1.9745x over previous
//
#include <hip/hip_runtime.h>

#define DIM 512
#define HIDDEN 1024
#define H2 2048        // 2*HIDDEN
#define NEXP 32
#define TOPK 4
#define TOKENS 64
#define NPAIR (TOKENS*TOPK)   // 256
#define PADK 8                // ushort pad per LDS row (2-way bank alias = free)

typedef __attribute__((ext_vector_type(8))) short short8;
typedef __attribute__((ext_vector_type(4))) float fp32x4;
typedef __attribute__((ext_vector_type(4))) unsigned short ushort4v;

// f32 -> bf16 round-nearest-even
__device__ __forceinline__ unsigned short f2bf_rne(float f) {
    unsigned u = __float_as_uint(f);
    return (unsigned short)((u + 0x7FFFu + ((u >> 16) & 1u)) >> 16);
}
// f32 -> packed (hi | lo<<16): hi = truncate-to-bf16, lo = RNE(residual)
__device__ __forceinline__ unsigned split2p(float f) {
    unsigned u = __float_as_uint(f);
    unsigned short h = (unsigned short)(u >> 16);
    float hf = __uint_as_float(u & 0xFFFF0000u);
    unsigned short lo = f2bf_rne(f - hf);
    return (unsigned)h | ((unsigned)lo << 16);
}

// ---------------- router: logits + top4 + softmax ----------------
__global__ void router_kernel(const float* __restrict__ x, const float* __restrict__ Wg,
                              const float* __restrict__ bg, int* __restrict__ idxw,
                              float* __restrict__ eww) {
    int b = blockIdx.x;
    int e = threadIdx.x;
    __shared__ float g[NEXP];
    if (e < NEXP) {
        const float* xr = x + b * DIM;
        const float* wr = Wg + e * DIM;
        float acc = 0.f;
        for (int d = 0; d < DIM; d += 4) {
            float4 xv = *(const float4*)(xr + d);
            float4 wv = *(const float4*)(wr + d);
            acc += xv.x*wv.x + xv.y*wv.y + xv.z*wv.z + xv.w*wv.w;
        }
        g[e] = acc + bg[e];
    }
    __syncthreads();
    if (threadIdx.x == 0) {
        int sel[TOPK]; float val[TOPK];
        bool used[NEXP];
        for (int i = 0; i < NEXP; ++i) used[i] = false;
        for (int k = 0; k < TOPK; ++k) {
            float best = -1e30f; int bi = 0;
            for (int ee = 0; ee < NEXP; ++ee) {
                if (!used[ee] && g[ee] > best) { best = g[ee]; bi = ee; }
            }
            used[bi] = true; sel[k] = bi; val[k] = best;
        }
        float m = val[0];
        float p[TOPK]; float s = 0.f;
        for (int k = 0; k < TOPK; ++k) { p[k] = __expf(val[k] - m); s += p[k]; }
        float inv = 1.f / s;
        for (int k = 0; k < TOPK; ++k) {
            idxw[b*TOPK + k] = sel[k];
            eww[b*TOPK + k]  = p[k] * inv;
        }
    }
}

// ---------------- deterministic per-expert list build ----------------
__global__ void build_lists(const int* __restrict__ idxw, int* __restrict__ counts,
                            int* __restrict__ lists) {
    int e = threadIdx.x;
    if (e >= NEXP) return;
    int cnt = 0;
    for (int p = 0; p < NPAIR; ++p) {
        if (idxw[p] == e) lists[e*TOKENS + cnt++] = p;
    }
    counts[e] = cnt;
}

// ---------------- expert up-proj + swiglu (MFMA, f32 split bf16 hi/lo) ----
// block = 256 thr = 4 waves; wave owns 16 raw w1 rows x 16 tokens.
// grid (NEXP, H2/64 = 32). 3 MFMAs per K-tile: wh*xh + wh*xl + wl*xh.
__global__ __launch_bounds__(256, 4) void expert_up(
        const float* __restrict__ x, const float* __restrict__ w1,
        const float* __restrict__ b1, const int* __restrict__ counts,
        const int* __restrict__ lists, float* __restrict__ act) {
    int e = blockIdx.x;
    int n = counts[e];
    if (n == 0) return;
    int tid = threadIdx.x;
    int wv = tid >> 6, l = tid & 63;
    int lr = l & 15, lg = l >> 4;          // A row-in-tile / k-group
    __shared__ unsigned short xh[16][DIM + PADK];   // 16.25 KB
    __shared__ unsigned short xl[16][DIM + PADK];   // 16.25 KB
    int r0 = blockIdx.y * 64 + wv * 16;    // raw row tile base (0..2047)
    const float* wbase = w1 + ((size_t)e*H2 + r0 + lr) * DIM + lg * 8;

    for (int t0 = 0; t0 < n; t0 += 16) {
        int nn = min(16, n - t0);
        __syncthreads();
        for (int i = tid; i < 16 * (DIM/4); i += 256) {
            int j = i >> 7, dd = i & 127;             // DIM/4 = 128
            float4 v = make_float4(0.f, 0.f, 0.f, 0.f);
            if (j < nn) {
                int p = lists[e*TOKENS + t0 + j];
                v = *(const float4*)(x + (size_t)(p >> 2)*DIM + 4*dd);
            }
            unsigned p0 = split2p(v.x), p1 = split2p(v.y);
            unsigned p2 = split2p(v.z), p3 = split2p(v.w);
            ushort4v hv, lv;
            hv[0] = (unsigned short)p0; lv[0] = (unsigned short)(p0 >> 16);
            hv[1] = (unsigned short)p1; lv[1] = (unsigned short)(p1 >> 16);
            hv[2] = (unsigned short)p2; lv[2] = (unsigned short)(p2 >> 16);
            hv[3] = (unsigned short)p3; lv[3] = (unsigned short)(p3 >> 16);
            *(ushort4v*)&xh[j][4*dd] = hv;
            *(ushort4v*)&xl[j][4*dd] = lv;
        }
        __syncthreads();

        fp32x4 acc = {0.f, 0.f, 0.f, 0.f};
        #pragma unroll 2
        for (int kt = 0; kt < 16; ++kt) {
            const float* wp = wbase + kt*32;
            fp32x4 wA = *(const fp32x4*)(wp);
            fp32x4 wB = *(const fp32x4*)(wp + 4);
            short8 ah, al;
            unsigned pk;
            pk = split2p(wA[0]); ah[0]=(short)(pk & 0xFFFF); al[0]=(short)(pk >> 16);
            pk = split2p(wA[1]); ah[1]=(short)(pk & 0xFFFF); al[1]=(short)(pk >> 16);
            pk = split2p(wA[2]); ah[2]=(short)(pk & 0xFFFF); al[2]=(short)(pk >> 16);
            pk = split2p(wA[3]); ah[3]=(short)(pk & 0xFFFF); al[3]=(short)(pk >> 16);
            pk = split2p(wB[0]); ah[4]=(short)(pk & 0xFFFF); al[4]=(short)(pk >> 16);
            pk = split2p(wB[1]); ah[5]=(short)(pk & 0xFFFF); al[5]=(short)(pk >> 16);
            pk = split2p(wB[2]); ah[6]=(short)(pk & 0xFFFF); al[6]=(short)(pk >> 16);
            pk = split2p(wB[3]); ah[7]=(short)(pk & 0xFFFF); al[7]=(short)(pk >> 16);
            short8 bh = *(const short8*)&xh[lr][kt*32 + lg*8];
            short8 bl = *(const short8*)&xl[lr][kt*32 + lg*8];
            acc = __builtin_amdgcn_mfma_f32_16x16x32_bf16(ah, bh, acc, 0, 0, 0);
            acc = __builtin_amdgcn_mfma_f32_16x16x32_bf16(ah, bl, acc, 0, 0, 0);
            acc = __builtin_amdgcn_mfma_f32_16x16x32_bf16(al, bh, acc, 0, 0, 0);
        }

        // D: col = l&15 = token, row = (l>>4)*4 + reg. Even row = glu, odd = lin
        // of channel rr/2, both in the SAME lane (regs 2u, 2u+1).
        int tok = lr;
        if (tok < nn) {
            int p = lists[e*TOKENS + t0 + tok];
            #pragma unroll
            for (int u = 0; u < 2; ++u) {
                int rr = r0 + lg*4 + 2*u;             // even raw row
                float h0 = acc[2*u]   + b1[e*H2 + rr];
                float h1 = acc[2*u+1] + b1[e*H2 + rr + 1];
                float gv = fminf(h0, 7.f);
                float lvv = fminf(fmaxf(h1, -7.f), 7.f);
                float sg = 1.f / (1.f + __expf(-1.702f * gv));
                act[(size_t)p*HIDDEN + (rr >> 1)] = gv * sg * (lvv + 1.f);
            }
        }
    }
}

// ---------------- expert down-proj (MFMA, w2 split hi/lo, act bf16) -------
// block = 256 thr = 4 waves; wave owns 16 w2 rows x 16 tokens.
// grid (NEXP, DIM/64 = 8). 2 MFMAs per K-tile: wh*a + wl*a.
__global__ __launch_bounds__(256, 4) void expert_down(
        const float* __restrict__ act, const float* __restrict__ w2,
        const float* __restrict__ b2, const int* __restrict__ counts,
        const int* __restrict__ lists, float* __restrict__ h2) {
    int e = blockIdx.x;
    int n = counts[e];
    if (n == 0) return;
    int tid = threadIdx.x;
    int wv = tid >> 6, l = tid & 63;
    int lr = l & 15, lg = l >> 4;
    __shared__ unsigned short as_[16][HIDDEN + PADK];  // 32.25 KB
    int r0 = blockIdx.y * 64 + wv * 16;    // output row tile base (0..511)
    const float* wbase = w2 + ((size_t)e*DIM + r0 + lr) * HIDDEN + lg * 8;

    for (int t0 = 0; t0 < n; t0 += 16) {
        int nn = min(16, n - t0);
        __syncthreads();
        for (int i = tid; i < 16 * (HIDDEN/4); i += 256) {
            int j = i >> 8, dd = i & 255;             // HIDDEN/4 = 256
            float4 v = make_float4(0.f, 0.f, 0.f, 0.f);
            if (j < nn) {
                int p = lists[e*TOKENS + t0 + j];
                v = *(const float4*)(act + (size_t)p*HIDDEN + 4*dd);
            }
            ushort4v hv;
            hv[0] = f2bf_rne(v.x); hv[1] = f2bf_rne(v.y);
            hv[2] = f2bf_rne(v.z); hv[3] = f2bf_rne(v.w);
            *(ushort4v*)&as_[j][4*dd] = hv;
        }
        __syncthreads();

        fp32x4 acc = {0.f, 0.f, 0.f, 0.f};
        #pragma unroll 2
        for (int kt = 0; kt < 32; ++kt) {
            const float* wp = wbase + kt*32;
            fp32x4 wA = *(const fp32x4*)(wp);
            fp32x4 wB = *(const fp32x4*)(wp + 4);
            short8 ah, al;
            unsigned pk;
            pk = split2p(wA[0]); ah[0]=(short)(pk & 0xFFFF); al[0]=(short)(pk >> 16);
            pk = split2p(wA[1]); ah[1]=(short)(pk & 0xFFFF); al[1]=(short)(pk >> 16);
            pk = split2p(wA[2]); ah[2]=(short)(pk & 0xFFFF); al[2]=(short)(pk >> 16);
            pk = split2p(wA[3]); ah[3]=(short)(pk & 0xFFFF); al[3]=(short)(pk >> 16);
            pk = split2p(wB[0]); ah[4]=(short)(pk & 0xFFFF); al[4]=(short)(pk >> 16);
            pk = split2p(wB[1]); ah[5]=(short)(pk & 0xFFFF); al[5]=(short)(pk >> 16);
            pk = split2p(wB[2]); ah[6]=(short)(pk & 0xFFFF); al[6]=(short)(pk >> 16);
            pk = split2p(wB[3]); ah[7]=(short)(pk & 0xFFFF); al[7]=(short)(pk >> 16);
            short8 bh = *(const short8*)&as_[lr][kt*32 + lg*8];
            acc = __builtin_amdgcn_mfma_f32_16x16x32_bf16(ah, bh, acc, 0, 0, 0);
            acc = __builtin_amdgcn_mfma_f32_16x16x32_bf16(al, bh, acc, 0, 0, 0);
        }

        int tok = lr;
        if (tok < nn) {
            int p = lists[e*TOKENS + t0 + tok];
            #pragma unroll
            for (int u = 0; u < 4; ++u) {
                int rr = r0 + lg*4 + u;
                h2[(size_t)p*DIM + rr] = acc[u] + b2[e*DIM + rr];
            }
        }
    }
}

// ---------------- weighted combine ----------------
__global__ void combine_kernel(const float* __restrict__ h2, const float* __restrict__ eww,
                               float* __restrict__ out) {
    int i = blockIdx.x * 256 + threadIdx.x;   // 0..32767
    int b = i / DIM;
    int c = i % DIM;
    float s = 0.f;
    #pragma unroll
    for (int k = 0; k < TOPK; ++k) {
        s += eww[b*TOPK + k] * h2[(size_t)(b*TOPK + k)*DIM + c];
    }
    out[i] = s;
}

extern "C" void kernel_launch(void* const* d_in, const int* in_sizes, int n_in,
                              void* d_out, int out_size, void* d_ws, size_t ws_size,
                              hipStream_t stream) {
    const float* x  = (const float*)d_in[0];
    const float* Wg = (const float*)d_in[1];
    const float* bg = (const float*)d_in[2];
    const float* w1 = (const float*)d_in[3];
    const float* b1 = (const float*)d_in[4];
    const float* w2 = (const float*)d_in[5];
    const float* b2 = (const float*)d_in[6];
    float* out = (float*)d_out;

    char* ws = (char*)d_ws;
    int*   idxw   = (int*)(ws);                 // 256 ints
    float* eww    = (float*)(ws + 1024);        // 256 floats
    int*   counts = (int*)(ws + 2048);          // 32 ints
    int*   lists  = (int*)(ws + 4096);          // 32*64 ints
    float* act    = (float*)(ws + 16384);                          // 256*1024 f32 = 1 MB
    float* h2     = (float*)(ws + 16384 + (size_t)NPAIR*HIDDEN*4); // 256*512 f32 = 512 KB

    router_kernel<<<TOKENS, 64, 0, stream>>>(x, Wg, bg, idxw, eww);
    build_lists<<<1, 32, 0, stream>>>(idxw, counts, lists);
    expert_up<<<dim3(NEXP, H2/64), 256, 0, stream>>>(x, w1, b1, counts, lists, act);
    expert_down<<<dim3(NEXP, DIM/64), 256, 0, stream>>>(act, w2, b2, counts, lists, h2);
    combine_kernel<<<TOKENS*DIM/256, 256, 0, stream>>>(h2, eww, out);
}